// Round 2
// baseline (1070.609 us; speedup 1.0000x reference)
//
#include <hip/hip_runtime.h>

#define LOSS_OFF 8388608
#define IDX_OFF  8388609

// ws layout (bytes)
#define WS_SEE   0          // float[1024]
#define WS_SXX   4096       // float[32768]
#define WS_IDX   135168     // int[32768]
#define WS_CNT   266240     // int
#define WS_LOSS  266248     // double
#define WS_WL    266256     // int[32768] -> ends 397328

#define FLT_BIG  3.402823466e+38f
#define MARGIN_Q 2.5e-4f

// numpy pairwise_sum of 256 squared elements, bit-exact:
// n=256 -> block(0..127) + block(128..255); each block: 8 accumulators,
// r[l]=a[l]; for i=8..120 step 8: r[l]+=a[i+l];
// res = ((r0+r1)+(r2+r3)) + ((r4+r5)+(r6+r7)). Squares rounded separately.
__device__ __forceinline__ float np_sumsq256(const float* __restrict__ p, int stride) {
    float s[2];
#pragma unroll
    for (int half = 0; half < 2; half++) {
        const float* a = p + half * 128 * stride;
        float r[8];
#pragma unroll
        for (int l = 0; l < 8; l++) {
            float v = a[l * stride];
            float sq = v * v;
            asm volatile("" : "+v"(sq));   // forbid fma contraction into the add chain
            r[l] = sq;
        }
#pragma unroll
        for (int i = 8; i < 128; i += 8) {
#pragma unroll
            for (int l = 0; l < 8; l++) {
                float v = a[(i + l) * stride];
                float sq = v * v;
                asm volatile("" : "+v"(sq));
                r[l] = r[l] + sq;
            }
        }
        s[half] = ((r[0] + r[1]) + (r[2] + r[3])) + ((r[4] + r[5]) + (r[6] + r[7]));
    }
    return s[0] + s[1];
}

// ---------------- k0: codebook ||e||^2 (np semantics) + init ----------------
__global__ __launch_bounds__(256) void k0_see(const float* __restrict__ emb,
                                              float* __restrict__ see,
                                              int* __restrict__ cnt,
                                              double* __restrict__ loss) {
    const int k = blockIdx.x * 256 + threadIdx.x;   // grid 4 x 256
    see[k] = np_sumsq256(emb + (size_t)k * 256, 1);
    if (k == 0) { *cnt = 0; *loss = 0.0; }
}

// ---------------- k_sxx: per-row ||x||^2 (np semantics) ----------------
__global__ __launch_bounds__(64) void k_sxx(const float* __restrict__ x,
                                            float* __restrict__ sxx) {
    const int n = blockIdx.x * 64 + threadIdx.x;    // grid 512 x 64
    const int b = n >> 10, hw = n & 1023;
    sxx[n] = np_sumsq256(x + (size_t)b * 262144 + hw, 1024);
}

// ---------------- k1: fp32 GEMM distances + np-rounded argmin + flag ----------------
// grid 256, block 512. Block tile: 128 rows x 1024 codes (4 k-tiles of 256).
__global__ __launch_bounds__(512) void k1_dist(const float* __restrict__ x,
                                               const float* __restrict__ emb,
                                               const float* __restrict__ see_g,
                                               const float* __restrict__ sxx_g,
                                               int* __restrict__ idx_ws,
                                               int* __restrict__ cnt,
                                               int* __restrict__ wl) {
    __shared__ float smem[12800];
    float* Xs   = smem;             // [c][r] : c*128 + r   (4096 floats)
    float* Es   = smem + 4096;      // [c][k] : c*256 + k   (8192 floats)
    float* sees = smem + 12288;     // [256]

    const int t   = threadIdx.x;
    const int blk = blockIdx.x;
    const int b    = blk >> 3;
    const int rem0 = (blk & 7) << 7;
    const float* xb = x + (size_t)b * 262144 + rem0;

    const int tr = t & 15;        // rows 8*tr .. 8*tr+7
    const int tk = t >> 4;        // codes 8*tk .. 8*tk+7 within 256-code tile

    float sx[8];
#pragma unroll
    for (int i = 0; i < 8; i++) sx[i] = sxx_g[blk * 128 + 8 * tr + i];

    float bm1[8], bm2[8]; int bi1[8];
#pragma unroll
    for (int i = 0; i < 8; i++) { bm1[i] = FLT_BIG; bm2[i] = FLT_BIG; bi1[i] = 0; }

    const int lw = t & 31;
    const int cg = t >> 5;

    for (int kt = 0; kt < 4; kt++) {
        float acc[8][8];
#pragma unroll
        for (int i = 0; i < 8; i++)
#pragma unroll
            for (int j = 0; j < 8; j++) acc[i][j] = 0.f;

        __syncthreads();
        if (t < 256) sees[t] = see_g[kt * 256 + t];

        for (int cc = 0; cc < 8; cc++) {
            const int cb = cc * 32;
            __syncthreads();
            {
                const float4 v0 = *(const float4*)(xb + (size_t)(cb + cg) * 1024 + 4 * lw);
                const float4 v1 = *(const float4*)(xb + (size_t)(cb + cg + 16) * 1024 + 4 * lw);
                *(float4*)(Xs + cg * 128 + 4 * lw)        = v0;
                *(float4*)(Xs + (cg + 16) * 128 + 4 * lw) = v1;
            }
            {
                const int ke = t & 63;
                const int cq = (t >> 6) << 2;
#pragma unroll
                for (int kk = 0; kk < 4; kk++) {
                    const int k = kk * 64 + ke;
                    const float4 ev = *(const float4*)(emb + (size_t)(kt * 256 + k) * 256 + cb + cq);
                    Es[(cq + 0) * 256 + k] = ev.x;
                    Es[(cq + 1) * 256 + k] = ev.y;
                    Es[(cq + 2) * 256 + k] = ev.z;
                    Es[(cq + 3) * 256 + k] = ev.w;
                }
            }
            __syncthreads();
            // sequential fp32 FMA chain over c (matches np sequential dot)
#pragma unroll 4
            for (int c = 0; c < 32; c++) {
                float a[8], bv[8];
                *(float4*)&a[0]  = *(const float4*)(Xs + c * 128 + 8 * tr);
                *(float4*)&a[4]  = *(const float4*)(Xs + c * 128 + 8 * tr + 4);
                *(float4*)&bv[0] = *(const float4*)(Es + c * 256 + 8 * tk);
                *(float4*)&bv[4] = *(const float4*)(Es + c * 256 + 8 * tk + 4);
#pragma unroll
                for (int i = 0; i < 8; i++)
#pragma unroll
                    for (int j = 0; j < 8; j++)
                        acc[i][j] = fmaf(a[i], bv[j], acc[i][j]);
            }
        }
        // np-rounded distance: q = fl(fl(sxx - 2*dot) + see)   (2*dot exact)
#pragma unroll
        for (int i = 0; i < 8; i++) {
#pragma unroll
            for (int j = 0; j < 8; j++) {
                const int k = kt * 256 + 8 * tk + j;
                const float t1 = fmaf(-2.f, acc[i][j], sx[i]);
                const float q  = t1 + sees[8 * tk + j];
                if (q < bm1[i])      { bm2[i] = bm1[i]; bm1[i] = q; bi1[i] = k; }
                else if (q < bm2[i]) { bm2[i] = q; }
            }
        }
    }

    // cross-thread reduction
    __syncthreads();
    float* rm1 = smem;                 // [128][33]
    float* rm2 = smem + 4224;
    int*   ri1 = (int*)(smem + 8448);
#pragma unroll
    for (int i = 0; i < 8; i++) {
        const int r = 8 * tr + i;
        rm1[r * 33 + tk] = bm1[i];
        rm2[r * 33 + tk] = bm2[i];
        ri1[r * 33 + tk] = bi1[i];
    }
    __syncthreads();
    if (t < 128) {
        const int r = t;
        float M1 = FLT_BIG, M2 = FLT_BIG; int I1 = 0x7fffffff;
        for (int g = 0; g < 32; g++) {
            const float m1 = rm1[r * 33 + g], m2 = rm2[r * 33 + g];
            const int   i1 = ri1[r * 33 + g];
            if (m1 < M1)      { M2 = fminf(M1, m2); M1 = m1; I1 = i1; }
            else if (m1 > M1) { M2 = fminf(M2, m1); }
            else              { I1 = min(I1, i1); M2 = m1; }
        }
        const int n = blk * 128 + r;
        idx_ws[n] = I1;
        if (M2 - M1 < MARGIN_Q) { const int slot = atomicAdd(cnt, 1); wl[slot] = n; }
    }
}

// ---------------- k2: re-resolve flagged rows with np fp32 semantics ----------------
__global__ __launch_bounds__(256) void k2_recheck(const float* __restrict__ x,
                                                  const float* __restrict__ emb,
                                                  const float* __restrict__ see_g,
                                                  const float* __restrict__ sxx_g,
                                                  int* __restrict__ idx_ws,
                                                  const int* __restrict__ cnt,
                                                  const int* __restrict__ wl) {
    __shared__ float xs[256];
    __shared__ float rv[256];
    __shared__ int   ri[256];
    const int t = threadIdx.x;
    const int count = *cnt;
    for (int e = blockIdx.x; e < count; e += gridDim.x) {
        const int n = wl[e];
        const int b = n >> 10, rem = n & 1023;
        const float sx = sxx_g[n];
        __syncthreads();
        xs[t] = x[(size_t)b * 262144 + (size_t)t * 1024 + rem];
        __syncthreads();
        float bv = FLT_BIG; int bi = 0x7fffffff;
        for (int jj = 0; jj < 4; jj++) {
            const int k = jj * 256 + t;
            const float* er = emb + (size_t)k * 256;
            float dot = 0.f;
            for (int c = 0; c < 256; c++) dot = fmaf(xs[c], er[c], dot);  // H1: sequential FMA
            const float t1 = fmaf(-2.f, dot, sx);
            const float q  = t1 + see_g[k];
            if (q < bv) { bv = q; bi = k; }        // ascending k: strict < keeps first
        }
        rv[t] = bv; ri[t] = bi;
        __syncthreads();
        for (int s = 128; s > 0; s >>= 1) {
            if (t < s) {
                if (rv[t + s] < rv[t] || (rv[t + s] == rv[t] && ri[t + s] < ri[t])) {
                    rv[t] = rv[t + s]; ri[t] = ri[t + s];
                }
            }
            __syncthreads();
        }
        if (t == 0) idx_ws[n] = ri[0];
        __syncthreads();
    }
}

// ---------------- k3: gather quantized + loss partials + indices ----------------
__global__ __launch_bounds__(256) void k3_out(const float* __restrict__ x,
                                              const float* __restrict__ emb,
                                              const int* __restrict__ idx_ws,
                                              float* __restrict__ dout,
                                              double* __restrict__ loss) {
    __shared__ float elds[32][257];
    __shared__ int   idxs[32];
    __shared__ float red[256];
    const int t  = threadIdx.x;
    const int bh = blockIdx.x;
    const int b = bh >> 5, h = bh & 31;
    if (t < 32) idxs[t] = idx_ws[(bh << 5) + t];
    __syncthreads();
    for (int r = 0; r < 32; r++) elds[r][t] = emb[(size_t)idxs[r] * 256 + t];
    __syncthreads();
    const int w = t & 31, cg = t >> 5;
    const size_t base = (size_t)b * 262144 + (size_t)(h * 32 + w);
    float acc = 0.f;
#pragma unroll 4
    for (int s = 0; s < 32; s++) {
        const int c = (cg << 5) + s;
        const float q  = elds[w][c];
        const float xv = x[base + (size_t)c * 1024];
        dout[base + (size_t)c * 1024] = q;
        const float d = q - xv;
        acc = fmaf(d, d, acc);
    }
    red[t] = acc;
    __syncthreads();
    for (int s = 128; s > 0; s >>= 1) {
        if (t < s) red[t] += red[t + s];
        __syncthreads();
    }
    if (t == 0) atomicAdd(loss, (double)red[0]);
    if (t < 32) dout[IDX_OFF + (bh << 5) + t] = (float)idxs[t];
}

// ---------------- k4: finalize loss ----------------
__global__ void k4_fin(const double* __restrict__ loss, float* __restrict__ dout) {
    dout[LOSS_OFF] = (float)(1.25 * (*loss) / 8388608.0);
}

extern "C" void kernel_launch(void* const* d_in, const int* in_sizes, int n_in,
                              void* d_out, int out_size, void* d_ws, size_t ws_size,
                              hipStream_t stream) {
    const float* x   = (const float*)d_in[0];
    const float* emb = (const float*)d_in[1];
    float* dout = (float*)d_out;
    char* ws = (char*)d_ws;
    float*  see  = (float*)(ws + WS_SEE);
    float*  sxx  = (float*)(ws + WS_SXX);
    int*    idxw = (int*)(ws + WS_IDX);
    int*    cnt  = (int*)(ws + WS_CNT);
    double* loss = (double*)(ws + WS_LOSS);
    int*    wl   = (int*)(ws + WS_WL);

    k0_see<<<4, 256, 0, stream>>>(emb, see, cnt, loss);
    k_sxx<<<512, 64, 0, stream>>>(x, sxx);
    k1_dist<<<256, 512, 0, stream>>>(x, emb, see, sxx, idxw, cnt, wl);
    k2_recheck<<<64, 256, 0, stream>>>(x, emb, see, sxx, idxw, cnt, wl);
    k3_out<<<1024, 256, 0, stream>>>(x, emb, idxw, dout, loss);
    k4_fin<<<1, 1, 0, stream>>>(loss, dout);
}

// Round 3
// 342.622 us; speedup vs baseline: 3.1248x; 3.1248x over previous
//
#include <hip/hip_runtime.h>

#define LOSS_OFF 8388608
#define IDX_OFF  8388609

// ws layout (bytes)
#define WS_SEE   0          // float[1024]
#define WS_SXX   4096       // float[32768]
#define WS_IDX   135168     // int[32768]
#define WS_LOSS  266240     // double (8-aligned)

#define FLT_BIG  3.402823466e+38f

// numpy pairwise_sum of 256 squared elements, bit-exact:
// n=256 -> block(0..127) + block(128..255); each block: 8 accumulators,
// r[l]=a[l]; for i=8..120 step 8: r[l]+=a[i+l];
// res = ((r0+r1)+(r2+r3)) + ((r4+r5)+(r6+r7)). Squares rounded separately.
__device__ __forceinline__ float np_sumsq256(const float* __restrict__ p, int stride) {
    float s[2];
#pragma unroll
    for (int half = 0; half < 2; half++) {
        const float* a = p + half * 128 * stride;
        float r[8];
#pragma unroll
        for (int l = 0; l < 8; l++) {
            float v = a[l * stride];
            float sq = v * v;
            asm volatile("" : "+v"(sq));   // forbid fma contraction into the add chain
            r[l] = sq;
        }
#pragma unroll
        for (int i = 8; i < 128; i += 8) {
#pragma unroll
            for (int l = 0; l < 8; l++) {
                float v = a[(i + l) * stride];
                float sq = v * v;
                asm volatile("" : "+v"(sq));
                r[l] = r[l] + sq;
            }
        }
        s[half] = ((r[0] + r[1]) + (r[2] + r[3])) + ((r[4] + r[5]) + (r[6] + r[7]));
    }
    return s[0] + s[1];
}

// ---------------- k0: codebook ||e||^2 (np semantics) + init ----------------
__global__ __launch_bounds__(256) void k0_see(const float* __restrict__ emb,
                                              float* __restrict__ see,
                                              double* __restrict__ loss) {
    const int k = blockIdx.x * 256 + threadIdx.x;   // grid 4 x 256
    see[k] = np_sumsq256(emb + (size_t)k * 256, 1);
    if (k == 0) { *loss = 0.0; }
}

// ---------------- k_sxx: per-row ||x||^2 (np semantics) ----------------
__global__ __launch_bounds__(64) void k_sxx(const float* __restrict__ x,
                                            float* __restrict__ sxx) {
    const int n = blockIdx.x * 64 + threadIdx.x;    // grid 512 x 64
    const int b = n >> 10, hw = n & 1023;
    sxx[n] = np_sumsq256(x + (size_t)b * 262144 + hw, 1024);
}

// ---------------- k1: fp32 GEMM distances + np-rounded argmin ----------------
// grid 256, block 512. Block tile: 128 rows x 1024 codes (4 k-tiles of 256).
// dot is a sequential fp32 FMA chain over c=0..255 (matches np reference).
__global__ __launch_bounds__(512) void k1_dist(const float* __restrict__ x,
                                               const float* __restrict__ emb,
                                               const float* __restrict__ see_g,
                                               const float* __restrict__ sxx_g,
                                               int* __restrict__ idx_ws) {
    __shared__ float smem[12800];
    float* Xs   = smem;             // [c][r] : c*128 + r   (4096 floats)
    float* Es   = smem + 4096;      // [c][k] : c*256 + k   (8192 floats)
    float* sees = smem + 12288;     // [256]

    const int t   = threadIdx.x;
    const int blk = blockIdx.x;
    const int b    = blk >> 3;
    const int rem0 = (blk & 7) << 7;
    const float* xb = x + (size_t)b * 262144 + rem0;

    const int tr = t & 15;        // rows 8*tr .. 8*tr+7
    const int tk = t >> 4;        // codes 8*tk .. 8*tk+7 within 256-code tile

    float sx[8];
#pragma unroll
    for (int i = 0; i < 8; i++) sx[i] = sxx_g[blk * 128 + 8 * tr + i];

    float bm1[8]; int bi1[8];
#pragma unroll
    for (int i = 0; i < 8; i++) { bm1[i] = FLT_BIG; bi1[i] = 0; }

    const int lw = t & 31;
    const int cg = t >> 5;

    for (int kt = 0; kt < 4; kt++) {
        float acc[8][8];
#pragma unroll
        for (int i = 0; i < 8; i++)
#pragma unroll
            for (int j = 0; j < 8; j++) acc[i][j] = 0.f;

        __syncthreads();
        if (t < 256) sees[t] = see_g[kt * 256 + t];

        for (int cc = 0; cc < 8; cc++) {
            const int cb = cc * 32;
            __syncthreads();
            {
                const float4 v0 = *(const float4*)(xb + (size_t)(cb + cg) * 1024 + 4 * lw);
                const float4 v1 = *(const float4*)(xb + (size_t)(cb + cg + 16) * 1024 + 4 * lw);
                *(float4*)(Xs + cg * 128 + 4 * lw)        = v0;
                *(float4*)(Xs + (cg + 16) * 128 + 4 * lw) = v1;
            }
            {
                const int ke = t & 63;
                const int cq = (t >> 6) << 2;
#pragma unroll
                for (int kk = 0; kk < 4; kk++) {
                    const int k = kk * 64 + ke;
                    const float4 ev = *(const float4*)(emb + (size_t)(kt * 256 + k) * 256 + cb + cq);
                    Es[(cq + 0) * 256 + k] = ev.x;
                    Es[(cq + 1) * 256 + k] = ev.y;
                    Es[(cq + 2) * 256 + k] = ev.z;
                    Es[(cq + 3) * 256 + k] = ev.w;
                }
            }
            __syncthreads();
            // sequential fp32 FMA chain over c (matches np sequential dot)
#pragma unroll 4
            for (int c = 0; c < 32; c++) {
                float a[8], bv[8];
                *(float4*)&a[0]  = *(const float4*)(Xs + c * 128 + 8 * tr);
                *(float4*)&a[4]  = *(const float4*)(Xs + c * 128 + 8 * tr + 4);
                *(float4*)&bv[0] = *(const float4*)(Es + c * 256 + 8 * tk);
                *(float4*)&bv[4] = *(const float4*)(Es + c * 256 + 8 * tk + 4);
#pragma unroll
                for (int i = 0; i < 8; i++)
#pragma unroll
                    for (int j = 0; j < 8; j++)
                        acc[i][j] = fmaf(a[i], bv[j], acc[i][j]);
            }
        }
        // np-rounded distance: q = fl(fl(sxx - 2*dot) + see)   (2*dot exact)
#pragma unroll
        for (int i = 0; i < 8; i++) {
#pragma unroll
            for (int j = 0; j < 8; j++) {
                const int k = kt * 256 + 8 * tk + j;
                const float t1 = fmaf(-2.f, acc[i][j], sx[i]);
                const float q  = t1 + sees[8 * tk + j];
                if (q < bm1[i]) { bm1[i] = q; bi1[i] = k; }   // ascending k: strict < keeps first
            }
        }
    }

    // cross-thread reduction (32 tk-groups per row)
    __syncthreads();
    float* rm1 = smem;                 // [128][33]
    int*   ri1 = (int*)(smem + 4224);
#pragma unroll
    for (int i = 0; i < 8; i++) {
        const int r = 8 * tr + i;
        rm1[r * 33 + tk] = bm1[i];
        ri1[r * 33 + tk] = bi1[i];
    }
    __syncthreads();
    if (t < 128) {
        const int r = t;
        float M1 = FLT_BIG; int I1 = 0x7fffffff;
        for (int g = 0; g < 32; g++) {
            const float m1 = rm1[r * 33 + g];
            const int   i1 = ri1[r * 33 + g];
            if (m1 < M1)      { M1 = m1; I1 = i1; }
            else if (m1 == M1){ I1 = min(I1, i1); }
        }
        idx_ws[blk * 128 + r] = I1;
    }
}

// ---------------- k3: gather quantized + loss partials + indices ----------------
__global__ __launch_bounds__(256) void k3_out(const float* __restrict__ x,
                                              const float* __restrict__ emb,
                                              const int* __restrict__ idx_ws,
                                              float* __restrict__ dout,
                                              double* __restrict__ loss) {
    __shared__ float elds[32][257];
    __shared__ int   idxs[32];
    __shared__ float red[256];
    const int t  = threadIdx.x;
    const int bh = blockIdx.x;
    const int b = bh >> 5, h = bh & 31;
    if (t < 32) idxs[t] = idx_ws[(bh << 5) + t];
    __syncthreads();
    for (int r = 0; r < 32; r++) elds[r][t] = emb[(size_t)idxs[r] * 256 + t];
    __syncthreads();
    const int w = t & 31, cg = t >> 5;
    const size_t base = (size_t)b * 262144 + (size_t)(h * 32 + w);
    float acc = 0.f;
#pragma unroll 4
    for (int s = 0; s < 32; s++) {
        const int c = (cg << 5) + s;
        const float q  = elds[w][c];
        const float xv = x[base + (size_t)c * 1024];
        dout[base + (size_t)c * 1024] = q;
        const float d = q - xv;
        acc = fmaf(d, d, acc);
    }
    red[t] = acc;
    __syncthreads();
    for (int s = 128; s > 0; s >>= 1) {
        if (t < s) red[t] += red[t + s];
        __syncthreads();
    }
    if (t == 0) atomicAdd(loss, (double)red[0]);
    if (t < 32) dout[IDX_OFF + (bh << 5) + t] = (float)idxs[t];
}

// ---------------- k4: finalize loss ----------------
__global__ void k4_fin(const double* __restrict__ loss, float* __restrict__ dout) {
    dout[LOSS_OFF] = (float)(1.25 * (*loss) / 8388608.0);
}

extern "C" void kernel_launch(void* const* d_in, const int* in_sizes, int n_in,
                              void* d_out, int out_size, void* d_ws, size_t ws_size,
                              hipStream_t stream) {
    const float* x   = (const float*)d_in[0];
    const float* emb = (const float*)d_in[1];
    float* dout = (float*)d_out;
    char* ws = (char*)d_ws;
    float*  see  = (float*)(ws + WS_SEE);
    float*  sxx  = (float*)(ws + WS_SXX);
    int*    idxw = (int*)(ws + WS_IDX);
    double* loss = (double*)(ws + WS_LOSS);

    k0_see<<<4, 256, 0, stream>>>(emb, see, loss);
    k_sxx<<<512, 64, 0, stream>>>(x, sxx);
    k1_dist<<<256, 512, 0, stream>>>(x, emb, see, sxx, idxw);
    k3_out<<<1024, 256, 0, stream>>>(x, emb, idxw, dout, loss);
    k4_fin<<<1, 1, 0, stream>>>(loss, dout);
}

// Round 4
// 330.465 us; speedup vs baseline: 3.2397x; 1.0368x over previous
//
#include <hip/hip_runtime.h>

#define LOSS_OFF 8388608
#define IDX_OFF  8388609

// ws layout (bytes)
#define WS_SEE   0          // float[1024]
#define WS_SXX   4096       // float[32768]           -> ends 135168
#define WS_KEY   135168     // u64[32768] packed (m,idx) -> ends 397312
#define WS_LOSS  397312     // double

#define FLT_BIG  3.402823466e+38f

// numpy pairwise_sum of 256 squared elements, bit-exact (see round-2 notes).
__device__ __forceinline__ float np_sumsq256(const float* __restrict__ p, int stride) {
    float s[2];
#pragma unroll
    for (int half = 0; half < 2; half++) {
        const float* a = p + half * 128 * stride;
        float r[8];
#pragma unroll
        for (int l = 0; l < 8; l++) {
            float v = a[l * stride];
            float sq = v * v;
            asm volatile("" : "+v"(sq));   // forbid fma contraction into the add chain
            r[l] = sq;
        }
#pragma unroll
        for (int i = 8; i < 128; i += 8) {
#pragma unroll
            for (int l = 0; l < 8; l++) {
                float v = a[(i + l) * stride];
                float sq = v * v;
                asm volatile("" : "+v"(sq));
                r[l] = r[l] + sq;
            }
        }
        s[half] = ((r[0] + r[1]) + (r[2] + r[3])) + ((r[4] + r[5]) + (r[6] + r[7]));
    }
    return s[0] + s[1];
}

__device__ __forceinline__ unsigned int f32_sortable(float m) {
    unsigned int u = __float_as_uint(m);
    return u ^ (((unsigned int)((int)u >> 31)) | 0x80000000u);
}

// ---------------- k0: codebook ||e||^2 (np semantics) + init ----------------
__global__ __launch_bounds__(256) void k0_see(const float* __restrict__ emb,
                                              float* __restrict__ see,
                                              double* __restrict__ loss) {
    const int k = blockIdx.x * 256 + threadIdx.x;   // grid 4 x 256
    see[k] = np_sumsq256(emb + (size_t)k * 256, 1);
    if (k == 0) { *loss = 0.0; }
}

// ---------------- k_sxx: per-row ||x||^2 (np semantics) + key init ----------------
__global__ __launch_bounds__(64) void k_sxx(const float* __restrict__ x,
                                            float* __restrict__ sxx,
                                            unsigned long long* __restrict__ key) {
    const int n = blockIdx.x * 64 + threadIdx.x;    // grid 512 x 64
    const int b = n >> 10, hw = n & 1023;
    sxx[n] = np_sumsq256(x + (size_t)b * 262144 + hw, 1024);
    key[n] = ~0ull;
}

// ---------------- k1: fp32 GEMM distances + np-rounded argmin ----------------
// grid 512 (= 256 row-blocks x 2 K-halves), block 512 threads.
// Block tile: 128 rows x 512 codes (2 kt-tiles of 256). 2 blocks/CU overlap barriers.
// dot is a sequential fp32 FMA chain over c=0..255 (matches np reference).
// Xs uses a chunk-rotate swizzle: 16B chunk m -> slot (m>>1)|((m&1)<<4), making
// the compute-loop reads 2-way (free) instead of 4-way bank-conflicted.
__global__ __launch_bounds__(512) void k1_dist(const float* __restrict__ x,
                                               const float* __restrict__ emb,
                                               const float* __restrict__ see_g,
                                               const float* __restrict__ sxx_g,
                                               unsigned long long* __restrict__ key) {
    __shared__ float smem[12800];
    float* Xs   = smem;             // swizzled [c][128]  (4096 floats)
    float* Es   = smem + 4096;      // [c][k] : c*256 + k (8192 floats)
    float* sees = smem + 12288;     // [256]

    const int t    = threadIdx.x;
    const int blk  = blockIdx.x;
    const int rb   = blk >> 1;      // row block 0..255
    const int half = blk & 1;       // K half
    const int b    = rb >> 3;
    const int rem0 = (rb & 7) << 7;
    const float* xb = x + (size_t)b * 262144 + rem0;

    const int tr = t & 15;        // rows 8*tr .. 8*tr+7
    const int tk = t >> 4;        // codes 8*tk .. 8*tk+7 within 256-code tile

    float sx[8];
#pragma unroll
    for (int i = 0; i < 8; i++) sx[i] = sxx_g[rb * 128 + 8 * tr + i];

    float bm1[8]; int bi1[8];
#pragma unroll
    for (int i = 0; i < 8; i++) { bm1[i] = FLT_BIG; bi1[i] = 0; }

    const int lw  = t & 31;
    const int cg  = t >> 5;
    const int slw = (lw >> 1) | ((lw & 1) << 4);   // rotate-swizzle slot for chunk lw

    for (int q = 0; q < 2; q++) {
        const int kt = half * 2 + q;
        float acc[8][8];
#pragma unroll
        for (int i = 0; i < 8; i++)
#pragma unroll
            for (int j = 0; j < 8; j++) acc[i][j] = 0.f;

        __syncthreads();
        if (t < 256) sees[t] = see_g[kt * 256 + t];

        for (int cc = 0; cc < 8; cc++) {
            const int cb = cc * 32;
            __syncthreads();
            // stage X^T (swizzled chunks)
            {
                const float4 v0 = *(const float4*)(xb + (size_t)(cb + cg) * 1024 + 4 * lw);
                const float4 v1 = *(const float4*)(xb + (size_t)(cb + cg + 16) * 1024 + 4 * lw);
                *(float4*)(Xs + cg * 128 + 4 * slw)        = v0;
                *(float4*)(Xs + (cg + 16) * 128 + 4 * slw) = v1;
            }
            // stage E^T
            {
                const int ke = t & 63;
                const int cq = (t >> 6) << 2;
#pragma unroll
                for (int kk = 0; kk < 4; kk++) {
                    const int k = kk * 64 + ke;
                    const float4 ev = *(const float4*)(emb + (size_t)(kt * 256 + k) * 256 + cb + cq);
                    Es[(cq + 0) * 256 + k] = ev.x;
                    Es[(cq + 1) * 256 + k] = ev.y;
                    Es[(cq + 2) * 256 + k] = ev.z;
                    Es[(cq + 3) * 256 + k] = ev.w;
                }
            }
            __syncthreads();
            // sequential fp32 FMA chain over c (matches np sequential dot)
#pragma unroll 4
            for (int c = 0; c < 32; c++) {
                float a[8], bv[8];
                *(float4*)&a[0]  = *(const float4*)(Xs + c * 128 + 4 * tr);        // slot tr   = rows 8tr..+3
                *(float4*)&a[4]  = *(const float4*)(Xs + c * 128 + 64 + 4 * tr);   // slot 16+tr = rows 8tr+4..+7
                *(float4*)&bv[0] = *(const float4*)(Es + c * 256 + 8 * tk);
                *(float4*)&bv[4] = *(const float4*)(Es + c * 256 + 8 * tk + 4);
#pragma unroll
                for (int i = 0; i < 8; i++)
#pragma unroll
                    for (int j = 0; j < 8; j++)
                        acc[i][j] = fmaf(a[i], bv[j], acc[i][j]);
            }
        }
        // np-rounded distance: q = fl(fl(sxx - 2*dot) + see)   (2*dot exact)
#pragma unroll
        for (int i = 0; i < 8; i++) {
#pragma unroll
            for (int j = 0; j < 8; j++) {
                const int k = kt * 256 + 8 * tk + j;
                const float t1 = fmaf(-2.f, acc[i][j], sx[i]);
                const float qd = t1 + sees[8 * tk + j];
                if (qd < bm1[i]) { bm1[i] = qd; bi1[i] = k; }   // ascending k: strict < keeps first
            }
        }
    }

    // cross-thread reduction (32 tk-groups per row), then cross-block atomic merge
    __syncthreads();
    float* rm1 = smem;                 // [128][33]
    int*   ri1 = (int*)(smem + 4224);
#pragma unroll
    for (int i = 0; i < 8; i++) {
        const int r = 8 * tr + i;
        rm1[r * 33 + tk] = bm1[i];
        ri1[r * 33 + tk] = bi1[i];
    }
    __syncthreads();
    if (t < 128) {
        const int r = t;
        float M1 = FLT_BIG; int I1 = 0x7fffffff;
        for (int g = 0; g < 32; g++) {
            const float m1 = rm1[r * 33 + g];
            const int   i1 = ri1[r * 33 + g];
            if (m1 < M1)       { M1 = m1; I1 = i1; }
            else if (m1 == M1) { I1 = min(I1, i1); }
        }
        const unsigned long long pk =
            ((unsigned long long)f32_sortable(M1) << 32) | (unsigned int)I1;
        atomicMin(&key[rb * 128 + r], pk);
    }
}

// ---------------- k3: gather quantized + loss partials + indices ----------------
__global__ __launch_bounds__(256) void k3_out(const float* __restrict__ x,
                                              const float* __restrict__ emb,
                                              const unsigned long long* __restrict__ key,
                                              float* __restrict__ dout,
                                              double* __restrict__ loss) {
    __shared__ float elds[32][257];
    __shared__ int   idxs[32];
    __shared__ float red[256];
    const int t  = threadIdx.x;
    const int bh = blockIdx.x;
    const int b = bh >> 5, h = bh & 31;
    if (t < 32) idxs[t] = (int)(key[(bh << 5) + t] & 0xffffffffull);
    __syncthreads();
    for (int r = 0; r < 32; r++) elds[r][t] = emb[(size_t)idxs[r] * 256 + t];
    __syncthreads();
    const int w = t & 31, cg = t >> 5;
    const size_t base = (size_t)b * 262144 + (size_t)(h * 32 + w);
    float acc = 0.f;
#pragma unroll 4
    for (int s = 0; s < 32; s++) {
        const int c = (cg << 5) + s;
        const float q  = elds[w][c];
        const float xv = x[base + (size_t)c * 1024];
        dout[base + (size_t)c * 1024] = q;
        const float d = q - xv;
        acc = fmaf(d, d, acc);
    }
    red[t] = acc;
    __syncthreads();
    for (int s = 128; s > 0; s >>= 1) {
        if (t < s) red[t] += red[t + s];
        __syncthreads();
    }
    if (t == 0) atomicAdd(loss, (double)red[0]);
    if (t < 32) dout[IDX_OFF + (bh << 5) + t] = (float)idxs[t];
}

// ---------------- k4: finalize loss ----------------
__global__ void k4_fin(const double* __restrict__ loss, float* __restrict__ dout) {
    dout[LOSS_OFF] = (float)(1.25 * (*loss) / 8388608.0);
}

extern "C" void kernel_launch(void* const* d_in, const int* in_sizes, int n_in,
                              void* d_out, int out_size, void* d_ws, size_t ws_size,
                              hipStream_t stream) {
    const float* x   = (const float*)d_in[0];
    const float* emb = (const float*)d_in[1];
    float* dout = (float*)d_out;
    char* ws = (char*)d_ws;
    float*  see  = (float*)(ws + WS_SEE);
    float*  sxx  = (float*)(ws + WS_SXX);
    unsigned long long* key = (unsigned long long*)(ws + WS_KEY);
    double* loss = (double*)(ws + WS_LOSS);

    k0_see<<<4, 256, 0, stream>>>(emb, see, loss);
    k_sxx<<<512, 64, 0, stream>>>(x, sxx, key);
    k1_dist<<<512, 512, 0, stream>>>(x, emb, see, sxx, key);
    k3_out<<<1024, 256, 0, stream>>>(x, emb, key, dout, loss);
    k4_fin<<<1, 1, 0, stream>>>(loss, dout);
}